// Round 10
// baseline (64.655 us; speedup 1.0000x reference)
//
#include <hip/hip_runtime.h>

// ---------------------------------------------------------------------------
// FNNAttention (Bahdanau additive attention). B=4, Q=256, M=256, QS=KS=H=512.
// out = tanh(query@Wo1^T + P@(memory@Wo2^T) + bo),  P = softmax(logits).
// TWO kernels (dispatch overhead dominates at this problem size):
//   1. gemm5 : fp32 inputs, in-register rne bf16 cvt, bf16 MFMA 16x16x32,
//              32x32/wave, k-split dual acc banks. Computes
//              Eq=exp2(TSC*(query@Wq^T+bq)), Ek=exp2(TSC*(memory@Wk^T+bk)),
//              Y1=query@Wo1^T+bo, Z=memory@Wo2^T.
//              Block 512 normalizes the mask (layout-detecting).
//   2. attn  : logits via rcp(Eq*Ek+1) (compacted unmasked-m list), softmax,
//              weights -> wout, out = tanh(Y1 + P@Z).
//              BYTE-IDENTICAL to the replay-proven R9 kernel.
// tanh(x) = 1 - 2/(exp2(TSC*x)+1), TSC = 2*log2(e).
// ---------------------------------------------------------------------------

#define B_   4
#define Q_   256
#define M_   256
#define H_   512
#define QS_  512
#define KS_  512

#define TSC 2.8853900817779268f

typedef __attribute__((ext_vector_type(8))) short bf16x8;
typedef __attribute__((ext_vector_type(4))) float f32x4;

__device__ __forceinline__ float fast_exp2(float x) { return __builtin_amdgcn_exp2f(x); }

__device__ __forceinline__ float tanh_fast(float x) {
    float e = fast_exp2(x * TSC);
    return 1.0f - 2.0f * __builtin_amdgcn_rcpf(e + 1.0f);
}

__device__ __forceinline__ unsigned short rne_bf16(float f) {
    unsigned b = __builtin_bit_cast(unsigned, f);
    return (unsigned short)((b + 0x7FFFu + ((b >> 16) & 1u)) >> 16);
}

__device__ __forceinline__ bf16x8 cvt8(const float* __restrict__ p) {
    const float4 lo = *(const float4*)p;
    const float4 hi = *(const float4*)(p + 4);
    float f[8] = {lo.x, lo.y, lo.z, lo.w, hi.x, hi.y, hi.z, hi.w};
    union { bf16x8 v; unsigned short u[8]; } r;
#pragma unroll
    for (int j = 0; j < 8; ++j) r.u[j] = rne_bf16(f[j]);
    return r.v;
}

// ---------------------------------------------------------------------------
// gemm5: four batched NT-GEMMs, fp32 sources with in-register bf16 cvt
// (values bit-identical to the staged-prep version). 32x32 per wave,
// k-split dual accumulator banks. seg = 0:Eq 1:Ek 2:Y1 3:Z.
// grid = 512 gemm blocks x 4 waves = 2048 wave-tiles + block 512 = mask norm.
// Fragment map: A/B lane l -> row/col = l&15, k = kt + (l>>4)*8 + j.
// D: reg j -> row (l>>4)*4+j, col l&15  [measured m89].
// ---------------------------------------------------------------------------
__global__ __launch_bounds__(256) void gemm5(const float* __restrict__ query,
                                             const float* __restrict__ memory,
                                             const float* __restrict__ Wq,
                                             const float* __restrict__ Wk,
                                             const float* __restrict__ Wo,
                                             const float* __restrict__ bq,
                                             const float* __restrict__ bk,
                                             const float* __restrict__ bo,
                                             const unsigned char* __restrict__ mask,
                                             int nmask,
                                             float* __restrict__ Eq,
                                             float* __restrict__ Ek,
                                             float* __restrict__ Y1,
                                             float* __restrict__ Z,
                                             int* __restrict__ maskN) {
    if (blockIdx.x == 512) {  // mask normalization (layout-detecting, r1-proven)
        __shared__ int flags[4];
        const int tid = threadIdx.x;
        int any = 0;
        for (int i = tid; i < nmask; i += 256)
            if ((i & 3) && mask[i]) any = 1;
        int wany = __any(any);
        if ((tid & 63) == 0) flags[tid >> 6] = wany ? 1 : 0;
        __syncthreads();
        const int isbool = flags[0] | flags[1] | flags[2] | flags[3];
        const int* ri = (const int*)mask;
        for (int i = tid; i < nmask; i += 256)
            maskN[i] = isbool ? (int)mask[i] : ri[i];
        return;
    }

    const int lane = threadIdx.x & 63;
    const int wid  = threadIdx.x >> 6;
    const int gt  = blockIdx.x * 4 + wid;  // 0..2047
    const int seg = gt >> 9;               // 0..3
    const int t   = gt & 511;
    const int tm  = t >> 4;                // 0..31
    const int tn  = t & 15;                // 0..15

    const float* A;
    const float* W;
    const float* bias;
    float* C;
    int ldW, wko;
    if (seg == 0)      { A = query;  W = Wq; ldW = 512;  wko = 0;   bias = bq; C = Eq; }
    else if (seg == 1) { A = memory; W = Wk; ldW = 512;  wko = 0;   bias = bk; C = Ek; }
    else if (seg == 2) { A = query;  W = Wo; ldW = 1024; wko = 0;   bias = bo; C = Y1; }
    else               { A = memory; W = Wo; ldW = 1024; wko = 512; bias = nullptr; C = Z; }

    const int rA = tm * 32 + (lane & 15);
    const int rB = tn * 32 + (lane & 15);
    const int ko = (lane >> 4) * 8;

    f32x4 p00 = {0,0,0,0}, p01 = {0,0,0,0}, p10 = {0,0,0,0}, p11 = {0,0,0,0};
    f32x4 q00 = {0,0,0,0}, q01 = {0,0,0,0}, q10 = {0,0,0,0}, q11 = {0,0,0,0};
#pragma unroll
    for (int kt = 0; kt < 256; kt += 32) {
        const int k0 = kt + ko;
        const int k1 = 256 + kt + ko;
        bf16x8 a0 = cvt8(&A[rA * 512 + k0]);
        bf16x8 a1 = cvt8(&A[(rA + 16) * 512 + k0]);
        bf16x8 b0 = cvt8(&W[rB * ldW + wko + k0]);
        bf16x8 b1 = cvt8(&W[(rB + 16) * ldW + wko + k0]);
        bf16x8 c0 = cvt8(&A[rA * 512 + k1]);
        bf16x8 c1 = cvt8(&A[(rA + 16) * 512 + k1]);
        bf16x8 d0 = cvt8(&W[rB * ldW + wko + k1]);
        bf16x8 d1 = cvt8(&W[(rB + 16) * ldW + wko + k1]);
        p00 = __builtin_amdgcn_mfma_f32_16x16x32_bf16(a0, b0, p00, 0, 0, 0);
        p01 = __builtin_amdgcn_mfma_f32_16x16x32_bf16(a0, b1, p01, 0, 0, 0);
        p10 = __builtin_amdgcn_mfma_f32_16x16x32_bf16(a1, b0, p10, 0, 0, 0);
        p11 = __builtin_amdgcn_mfma_f32_16x16x32_bf16(a1, b1, p11, 0, 0, 0);
        q00 = __builtin_amdgcn_mfma_f32_16x16x32_bf16(c0, d0, q00, 0, 0, 0);
        q01 = __builtin_amdgcn_mfma_f32_16x16x32_bf16(c0, d1, q01, 0, 0, 0);
        q10 = __builtin_amdgcn_mfma_f32_16x16x32_bf16(c1, d0, q10, 0, 0, 0);
        q11 = __builtin_amdgcn_mfma_f32_16x16x32_bf16(c1, d1, q11, 0, 0, 0);
    }
    const int col = tn * 32 + (lane & 15);
    const int r0  = tm * 32 + (lane >> 4) * 4;
    const float bv0 = bias ? bias[col] : 0.f;
    const float bv1 = bias ? bias[col + 16] : 0.f;
    if (seg < 2) {
#pragma unroll
        for (int j = 0; j < 4; ++j) {
            C[(r0 + j) * 512 + col]           = fast_exp2(TSC * (p00[j] + q00[j] + bv0));
            C[(r0 + j) * 512 + col + 16]      = fast_exp2(TSC * (p01[j] + q01[j] + bv1));
            C[(r0 + 16 + j) * 512 + col]      = fast_exp2(TSC * (p10[j] + q10[j] + bv0));
            C[(r0 + 16 + j) * 512 + col + 16] = fast_exp2(TSC * (p11[j] + q11[j] + bv1));
        }
    } else {
#pragma unroll
        for (int j = 0; j < 4; ++j) {
            C[(r0 + j) * 512 + col]           = p00[j] + q00[j] + bv0;
            C[(r0 + j) * 512 + col + 16]      = p01[j] + q01[j] + bv1;
            C[(r0 + 16 + j) * 512 + col]      = p10[j] + q10[j] + bv0;
            C[(r0 + 16 + j) * 512 + col + 16] = p11[j] + q11[j] + bv1;
        }
    }
}

// ---------------------------------------------------------------------------
// attn: logits + softmax + final output. Block = (b, 4 q-rows), 1024 threads.
// BYTE-IDENTICAL to the replay-proven R9 kernel.
// ---------------------------------------------------------------------------
__global__ __launch_bounds__(1024) void attn_fused(const int* __restrict__ maskN,
                                                   const float* __restrict__ Eq,
                                                   const float* __restrict__ Ek,
                                                   const float* __restrict__ Wl,
                                                   const float* __restrict__ bl,
                                                   const float* __restrict__ Y1,
                                                   const float* __restrict__ Z,
                                                   float* __restrict__ wout,
                                                   float* __restrict__ out) {
    const int b = blockIdx.y;
    const int q0 = blockIdx.x * 4;
    const int tid = threadIdx.x;
    const int wid = tid >> 6;
    const int lane = tid & 63;

    __shared__ float slog[4][M_];
    __shared__ float swt[4][M_];
    __shared__ int s_list[M_];
    __shared__ int s_base[4];
    __shared__ int s_cnt;
    __shared__ int s_allmask;

    // ---- phase 0: compact unmasked m list ----
    int msk_ = 1, prefix_ = 0;
    if (tid < 256) {
        msk_ = maskN[(b << 8) + tid];
        unsigned long long vote = __ballot(msk_ == 0);
        prefix_ = __popcll(vote & ((1ull << lane) - 1ull));
        if (lane == 0) s_base[wid] = __popcll(vote);
    }
    __syncthreads();
    if (tid == 0) {
        int s = 0;
#pragma unroll
        for (int i = 0; i < 4; ++i) { int c = s_base[i]; s_base[i] = s; s += c; }
        s_cnt = s;
    }
    __syncthreads();
    if (tid < 256 && !msk_) s_list[s_base[wid] + prefix_] = tid;

    // per-lane register slices (Eq already exponentiated)
    float qreg[4][8], wlr[8];
#pragma unroll
    for (int qi = 0; qi < 4; ++qi) {
        const float* qp = &Eq[((b << 8) + (q0 + qi)) * H_ + lane * 8];
        *(float4*)&qreg[qi][0] = *(const float4*)qp;
        *(float4*)&qreg[qi][4] = *(const float4*)(qp + 4);
    }
    *(float4*)&wlr[0] = *(const float4*)&Wl[lane * 8];
    *(float4*)&wlr[4] = *(const float4*)&Wl[lane * 8 + 4];
    const float bl0 = bl[0];

    float sumWL = wlr[0] + wlr[1] + wlr[2] + wlr[3] + wlr[4] + wlr[5] + wlr[6] + wlr[7];
#pragma unroll
    for (int off = 32; off; off >>= 1) sumWL += __shfl_xor(sumWL, off, 64);

    __syncthreads();
    const int cnt = s_cnt;

    // ---- phase 1: logits over compacted list (1 rcp per element) ----
    for (int idx = wid; idx < cnt; idx += 16) {
        const int m = s_list[idx];
        float kr[8];
        const float* kp = &Ek[((b << 8) + m) * H_ + lane * 8];
        *(float4*)&kr[0] = *(const float4*)kp;
        *(float4*)&kr[4] = *(const float4*)(kp + 4);
        float acc[4] = {0.f, 0.f, 0.f, 0.f};
#pragma unroll
        for (int h = 0; h < 8; ++h) {
            const float ek = kr[h];
            const float wv = wlr[h];
#pragma unroll
            for (int qi = 0; qi < 4; ++qi) {
                const float e = qreg[qi][h] * ek;
                const float r = __builtin_amdgcn_rcpf(e + 1.0f);
                acc[qi] = fmaf(wv, r, acc[qi]);
            }
        }
#pragma unroll
        for (int qi = 0; qi < 4; ++qi) {
            float v = acc[qi];
#pragma unroll
            for (int off = 32; off; off >>= 1) v += __shfl_xor(v, off, 64);
            if (lane == 0) slog[qi][m] = sumWL - 2.0f * v + bl0;
        }
    }
    __syncthreads();

    // ---- phase 2: softmax (wave wid < 4 owns row q0+wid) ----
    if (wid < 4) {
        const int qi = wid;
        float x[4];
        int mk[4];
#pragma unroll
        for (int j = 0; j < 4; ++j) {
            const int m = lane * 4 + j;
            mk[j] = maskN[(b << 8) + m];
            x[j] = mk[j] ? -1e30f : slog[qi][m];
        }
        float mx = fmaxf(fmaxf(x[0], x[1]), fmaxf(x[2], x[3]));
#pragma unroll
        for (int off = 32; off; off >>= 1) mx = fmaxf(mx, __shfl_xor(mx, off, 64));
        float e[4], s = 0.f;
#pragma unroll
        for (int j = 0; j < 4; ++j) {
            e[j] = mk[j] ? 0.f : fast_exp2((x[j] - mx) * 1.4426950408889634f);
            s += e[j];
        }
#pragma unroll
        for (int off = 32; off; off >>= 1) s += __shfl_xor(s, off, 64);
        float w4[4];
        if (s > 0.f) {
            const float inv = 1.0f / s;
#pragma unroll
            for (int j = 0; j < 4; ++j) w4[j] = e[j] * inv;
        } else {
#pragma unroll
            for (int j = 0; j < 4; ++j) w4[j] = 1.0f / (float)M_;
        }
#pragma unroll
        for (int j = 0; j < 4; ++j) swt[qi][lane * 4 + j] = w4[j];
        *(float4*)&wout[((b << 8) + (q0 + qi)) * M_ + lane * 4] = *(const float4*)w4;
        if (tid == 0) s_allmask = (s <= 0.f) ? 1 : 0;
    }
    __syncthreads();

    // ---- phase 3: out[q][d] = tanh(Y1[q][d] + sum_m swt[q][m]*Z[b][m][d]),
    // all 1024 threads: tid<512 -> q-rows {0,1}, tid>=512 -> {2,3}. ----
    {
        const int am = s_allmask;
        const int d = tid & 511;
        const int qp = (tid >> 9) << 1;        // 0 or 2
        const float* Zb = &Z[((b << 8)) * QS_ + d];
        float a0 = 0.f, a1 = 0.f;
        if (!am) {
            for (int idx = 0; idx < cnt; ++idx) {
                const int m = s_list[idx];
                const float zv = Zb[m * QS_];
                a0 = fmaf(swt[qp][m], zv, a0);
                a1 = fmaf(swt[qp + 1][m], zv, a1);
            }
        } else {
            for (int m = 0; m < M_; ++m) {
                const float zv = Zb[m * QS_];
                a0 = fmaf(swt[qp][m], zv, a0);
                a1 = fmaf(swt[qp + 1][m], zv, a1);
            }
        }
        const int r0 = (b << 8) + q0 + qp;
        out[r0 * QS_ + d]        = tanh_fast(Y1[r0 * QS_ + d] + a0);
        out[(r0 + 1) * QS_ + d]  = tanh_fast(Y1[(r0 + 1) * QS_ + d] + a1);
    }
}

// ---------------------------------------------------------------------------
extern "C" void kernel_launch(void* const* d_in, const int* in_sizes, int n_in,
                              void* d_out, int out_size, void* d_ws, size_t ws_size,
                              hipStream_t stream) {
    const float* query  = (const float*)d_in[0];
    const float* memory = (const float*)d_in[1];
    const void*  mask   = d_in[2];
    const float* Wk = (const float*)d_in[3];
    const float* bk = (const float*)d_in[4];
    const float* Wq = (const float*)d_in[5];
    const float* bq = (const float*)d_in[6];
    const float* Wl = (const float*)d_in[7];
    const float* bl = (const float*)d_in[8];
    const float* Wo = (const float*)d_in[9];
    const float* bo = (const float*)d_in[10];

    float* out  = (float*)d_out;                 // [4,256,512]
    float* wout = out + B_ * Q_ * QS_;           // [4,256,256]

    float* ws = (float*)d_ws;
    float* Eq    = ws;                           // 524288 f32
    float* Ek    = ws + 524288;                  // 524288 f32
    float* Y1    = ws + 1048576;                 // 524288 f32
    float* Z     = ws + 1572864;                 // 524288 f32
    int*   maskN = (int*)(ws + 2097152);         // 1024 int

    hipLaunchKernelGGL(gemm5, dim3(513), dim3(256), 0, stream,
                       query, memory, Wq, Wk, Wo, bq, bk, bo,
                       (const unsigned char*)mask, in_sizes[2],
                       Eq, Ek, Y1, Z, maskN);
    hipLaunchKernelGGL(attn_fused, dim3(Q_ / 4, B_), dim3(1024), 0, stream,
                       maskN, Eq, Ek, Wl, bl, Y1, Z, wout, out);
}

// Round 11
// 55.495 us; speedup vs baseline: 1.1651x; 1.1651x over previous
//
#include <hip/hip_runtime.h>

// ---------------------------------------------------------------------------
// FNNAttention (Bahdanau additive attention). B=4, Q=256, M=256, QS=KS=H=512.
// out = tanh(query@Wo1^T + P@(memory@Wo2^T) + bo),  P = softmax(logits).
// Structure = proven R8 (55.5us) with Eq/Ek/Z stored as bf16 (halves the
// attn kernel's L2 streams; control flow unchanged):
//   1. prep  : fp32->bf16 of query/memory/Wq/Wk/Wo + mask norm
//   2. gemm5 : Eq=exp2(TSC*(query@Wq^T+bq)) [bf16], Ek=... [bf16],
//              Y1=query@Wo1^T+bo [f32], Z=memory@Wo2^T [bf16]
//              (bf16 MFMA 16x16x32, 32x32/wave)
//   3. attn  : logits via rcp(Eq*Ek+1) (compacted unmasked-m list), softmax,
//              weights -> wout, out = tanh(Y1 + P@Z). R8 control flow.
// tanh(x) = 1 - 2/(exp2(TSC*x)+1), TSC = 2*log2(e).
// ---------------------------------------------------------------------------

#define B_   4
#define Q_   256
#define M_   256
#define H_   512
#define QS_  512
#define KS_  512

#define TSC 2.8853900817779268f

typedef __attribute__((ext_vector_type(8))) short bf16x8;
typedef __attribute__((ext_vector_type(4))) float f32x4;

__device__ __forceinline__ float fast_exp2(float x) { return __builtin_amdgcn_exp2f(x); }

__device__ __forceinline__ float tanh_fast(float x) {
    float e = fast_exp2(x * TSC);
    return 1.0f - 2.0f * __builtin_amdgcn_rcpf(e + 1.0f);
}

__device__ __forceinline__ unsigned short rne_bf16(float f) {
    unsigned b = __builtin_bit_cast(unsigned, f);
    return (unsigned short)((b + 0x7FFFu + ((b >> 16) & 1u)) >> 16);
}

__device__ __forceinline__ float bf2f(unsigned short u) {
    return __builtin_bit_cast(float, (unsigned)u << 16);
}

__device__ __forceinline__ bf16x8 cvt8(const float* __restrict__ p) {
    const float4 lo = *(const float4*)p;
    const float4 hi = *(const float4*)(p + 4);
    float f[8] = {lo.x, lo.y, lo.z, lo.w, hi.x, hi.y, hi.z, hi.w};
    union { bf16x8 v; unsigned short u[8]; } r;
#pragma unroll
    for (int j = 0; j < 8; ++j) r.u[j] = rne_bf16(f[j]);
    return r.v;
}

// ---------------------------------------------------------------------------
// prep: blocks 0..1023 convert 2.1M floats -> bf16 (8 per thread);
// block 1024 normalizes the mask (layout-detecting, validated round 1).
// ---------------------------------------------------------------------------
__global__ __launch_bounds__(256) void prep(const float* __restrict__ query,
                                            const float* __restrict__ memory,
                                            const float* __restrict__ Wq,
                                            const float* __restrict__ Wk,
                                            const float* __restrict__ Wo,
                                            const unsigned char* __restrict__ mask,
                                            unsigned short* __restrict__ qbf,
                                            unsigned short* __restrict__ mbf,
                                            unsigned short* __restrict__ wqbf,
                                            unsigned short* __restrict__ wkbf,
                                            unsigned short* __restrict__ wobf,
                                            int* __restrict__ maskN, int nmask) {
    if (blockIdx.x == 1024) {
        __shared__ int flags[4];
        const int tid = threadIdx.x;
        int any = 0;
        for (int i = tid; i < nmask; i += 256)
            if ((i & 3) && mask[i]) any = 1;
        int wany = __any(any);
        if ((tid & 63) == 0) flags[tid >> 6] = wany ? 1 : 0;
        __syncthreads();
        const int isbool = flags[0] | flags[1] | flags[2] | flags[3];
        const int* ri = (const int*)mask;
        for (int i = tid; i < nmask; i += 256)
            maskN[i] = isbool ? (int)mask[i] : ri[i];
        return;
    }
    const int u = blockIdx.x * 256 + threadIdx.x;
    const float* src;
    unsigned short* dst;
    int off;
    if (u < 131072) {
        if (u < 65536) { src = query;  dst = qbf; off = u; }
        else           { src = memory; dst = mbf; off = u - 65536; }
    } else if (u < 196608) {
        if (u < 163840) { src = Wq; dst = wqbf; off = u - 131072; }
        else            { src = Wk; dst = wkbf; off = u - 163840; }
    } else { src = Wo; dst = wobf; off = u - 196608; }
    const int i = off * 8;
    *(bf16x8*)&dst[i] = cvt8(&src[i]);
}

// ---------------------------------------------------------------------------
// gemm5: four batched NT-GEMMs, 32x32 per wave, bf16 MFMA 16x16x32.
// seg = 0:Eq(bf16) 1:Ek(bf16) 2:Y1(f32) 3:Z(bf16).
// grid = 512 blocks x 4 waves = 2048 wave-tiles (512 per seg).
// Fragment map: A/B lane l -> row/col = l&15, k = kt + (l>>4)*8 + j.
// D: reg j -> row (l>>4)*4+j, col l&15  [measured m89].
// ---------------------------------------------------------------------------
__global__ __launch_bounds__(256) void gemm5(const unsigned short* __restrict__ qbf,
                                             const unsigned short* __restrict__ mbf,
                                             const unsigned short* __restrict__ wqbf,
                                             const unsigned short* __restrict__ wkbf,
                                             const unsigned short* __restrict__ wobf,
                                             const float* __restrict__ bq,
                                             const float* __restrict__ bk,
                                             const float* __restrict__ bo,
                                             unsigned short* __restrict__ Eqb,
                                             unsigned short* __restrict__ Ekb,
                                             float* __restrict__ Y1,
                                             unsigned short* __restrict__ Zb) {
    const int lane = threadIdx.x & 63;
    const int wid  = threadIdx.x >> 6;
    const int gt  = blockIdx.x * 4 + wid;  // 0..2047
    const int seg = gt >> 9;               // 0..3
    const int t   = gt & 511;
    const int tm  = t >> 4;                // 0..31
    const int tn  = t & 15;                // 0..15

    const unsigned short* A;
    const unsigned short* W;
    const float* bias;
    int ldW, wko;
    if (seg == 0)      { A = qbf; W = wqbf; ldW = 512;  wko = 0;   bias = bq; }
    else if (seg == 1) { A = mbf; W = wkbf; ldW = 512;  wko = 0;   bias = bk; }
    else if (seg == 2) { A = qbf; W = wobf; ldW = 1024; wko = 0;   bias = bo; }
    else               { A = mbf; W = wobf; ldW = 1024; wko = 512; bias = nullptr; }

    const int rA = tm * 32 + (lane & 15);
    const int rB = tn * 32 + (lane & 15);
    const int ko = (lane >> 4) * 8;

    f32x4 acc00 = {0,0,0,0}, acc01 = {0,0,0,0}, acc10 = {0,0,0,0}, acc11 = {0,0,0,0};
#pragma unroll
    for (int kt = 0; kt < 512; kt += 32) {
        bf16x8 a0 = *(const bf16x8*)&A[rA * 512 + kt + ko];
        bf16x8 a1 = *(const bf16x8*)&A[(rA + 16) * 512 + kt + ko];
        bf16x8 b0 = *(const bf16x8*)&W[rB * ldW + wko + kt + ko];
        bf16x8 b1 = *(const bf16x8*)&W[(rB + 16) * ldW + wko + kt + ko];
        acc00 = __builtin_amdgcn_mfma_f32_16x16x32_bf16(a0, b0, acc00, 0, 0, 0);
        acc01 = __builtin_amdgcn_mfma_f32_16x16x32_bf16(a0, b1, acc01, 0, 0, 0);
        acc10 = __builtin_amdgcn_mfma_f32_16x16x32_bf16(a1, b0, acc10, 0, 0, 0);
        acc11 = __builtin_amdgcn_mfma_f32_16x16x32_bf16(a1, b1, acc11, 0, 0, 0);
    }
    const int col = tn * 32 + (lane & 15);
    const int r0  = tm * 32 + (lane >> 4) * 4;
    const float bv0 = bias ? bias[col] : 0.f;
    const float bv1 = bias ? bias[col + 16] : 0.f;
    if (seg < 2) {
        unsigned short* E = (seg == 0) ? Eqb : Ekb;
#pragma unroll
        for (int j = 0; j < 4; ++j) {
            E[(r0 + j) * 512 + col]           = rne_bf16(fast_exp2(TSC * (acc00[j] + bv0)));
            E[(r0 + j) * 512 + col + 16]      = rne_bf16(fast_exp2(TSC * (acc01[j] + bv1)));
            E[(r0 + 16 + j) * 512 + col]      = rne_bf16(fast_exp2(TSC * (acc10[j] + bv0)));
            E[(r0 + 16 + j) * 512 + col + 16] = rne_bf16(fast_exp2(TSC * (acc11[j] + bv1)));
        }
    } else if (seg == 2) {
#pragma unroll
        for (int j = 0; j < 4; ++j) {
            Y1[(r0 + j) * 512 + col]           = acc00[j] + bv0;
            Y1[(r0 + j) * 512 + col + 16]      = acc01[j] + bv1;
            Y1[(r0 + 16 + j) * 512 + col]      = acc10[j] + bv0;
            Y1[(r0 + 16 + j) * 512 + col + 16] = acc11[j] + bv1;
        }
    } else {
#pragma unroll
        for (int j = 0; j < 4; ++j) {
            Zb[(r0 + j) * 512 + col]           = rne_bf16(acc00[j]);
            Zb[(r0 + j) * 512 + col + 16]      = rne_bf16(acc01[j]);
            Zb[(r0 + 16 + j) * 512 + col]      = rne_bf16(acc10[j]);
            Zb[(r0 + 16 + j) * 512 + col + 16] = rne_bf16(acc11[j]);
        }
    }
}

// ---------------------------------------------------------------------------
// attn: logits + softmax + final output. Block = (b, 4 q-rows), 1024 threads.
// Control flow byte-identical to the replay-proven R8 kernel; only the
// Eq/Ek/Z load dtypes changed to bf16.
// ---------------------------------------------------------------------------
__global__ __launch_bounds__(1024) void attn_fused(const int* __restrict__ maskN,
                                                   const unsigned short* __restrict__ Eqb,
                                                   const unsigned short* __restrict__ Ekb,
                                                   const float* __restrict__ Wl,
                                                   const float* __restrict__ bl,
                                                   const float* __restrict__ Y1,
                                                   const unsigned short* __restrict__ Zb,
                                                   float* __restrict__ wout,
                                                   float* __restrict__ out) {
    const int b = blockIdx.y;
    const int q0 = blockIdx.x * 4;
    const int tid = threadIdx.x;
    const int wid = tid >> 6;
    const int lane = tid & 63;

    __shared__ float slog[4][M_];
    __shared__ float swt[4][M_];
    __shared__ int s_list[M_];
    __shared__ int s_base[4];
    __shared__ int s_cnt;
    __shared__ int s_allmask;

    // ---- phase 0: compact unmasked m list ----
    int msk_ = 1, prefix_ = 0;
    if (tid < 256) {
        msk_ = maskN[(b << 8) + tid];
        unsigned long long vote = __ballot(msk_ == 0);
        prefix_ = __popcll(vote & ((1ull << lane) - 1ull));
        if (lane == 0) s_base[wid] = __popcll(vote);
    }
    __syncthreads();
    if (tid == 0) {
        int s = 0;
#pragma unroll
        for (int i = 0; i < 4; ++i) { int c = s_base[i]; s_base[i] = s; s += c; }
        s_cnt = s;
    }
    __syncthreads();
    if (tid < 256 && !msk_) s_list[s_base[wid] + prefix_] = tid;

    // per-lane register slices (Eq already exponentiated, bf16)
    float qreg[4][8], wlr[8];
#pragma unroll
    for (int qi = 0; qi < 4; ++qi) {
        union { bf16x8 v; unsigned short u[8]; } qv;
        qv.v = *(const bf16x8*)&Eqb[((b << 8) + (q0 + qi)) * H_ + lane * 8];
#pragma unroll
        for (int h = 0; h < 8; ++h) qreg[qi][h] = bf2f(qv.u[h]);
    }
    *(float4*)&wlr[0] = *(const float4*)&Wl[lane * 8];
    *(float4*)&wlr[4] = *(const float4*)&Wl[lane * 8 + 4];
    const float bl0 = bl[0];

    float sumWL = wlr[0] + wlr[1] + wlr[2] + wlr[3] + wlr[4] + wlr[5] + wlr[6] + wlr[7];
#pragma unroll
    for (int off = 32; off; off >>= 1) sumWL += __shfl_xor(sumWL, off, 64);

    __syncthreads();
    const int cnt = s_cnt;

    // ---- phase 1: logits over compacted list (1 rcp per element) ----
    for (int idx = wid; idx < cnt; idx += 16) {
        const int m = s_list[idx];
        union { bf16x8 v; unsigned short u[8]; } kv;
        kv.v = *(const bf16x8*)&Ekb[((b << 8) + m) * H_ + lane * 8];
        float acc[4] = {0.f, 0.f, 0.f, 0.f};
#pragma unroll
        for (int h = 0; h < 8; ++h) {
            const float ek = bf2f(kv.u[h]);
            const float wv = wlr[h];
#pragma unroll
            for (int qi = 0; qi < 4; ++qi) {
                const float e = qreg[qi][h] * ek;
                const float r = __builtin_amdgcn_rcpf(e + 1.0f);
                acc[qi] = fmaf(wv, r, acc[qi]);
            }
        }
#pragma unroll
        for (int qi = 0; qi < 4; ++qi) {
            float v = acc[qi];
#pragma unroll
            for (int off = 32; off; off >>= 1) v += __shfl_xor(v, off, 64);
            if (lane == 0) slog[qi][m] = sumWL - 2.0f * v + bl0;
        }
    }
    __syncthreads();

    // ---- phase 2: softmax (wave wid < 4 owns row q0+wid) ----
    if (wid < 4) {
        const int qi = wid;
        float x[4];
        int mk[4];
#pragma unroll
        for (int j = 0; j < 4; ++j) {
            const int m = lane * 4 + j;
            mk[j] = maskN[(b << 8) + m];
            x[j] = mk[j] ? -1e30f : slog[qi][m];
        }
        float mx = fmaxf(fmaxf(x[0], x[1]), fmaxf(x[2], x[3]));
#pragma unroll
        for (int off = 32; off; off >>= 1) mx = fmaxf(mx, __shfl_xor(mx, off, 64));
        float e[4], s = 0.f;
#pragma unroll
        for (int j = 0; j < 4; ++j) {
            e[j] = mk[j] ? 0.f : fast_exp2((x[j] - mx) * 1.4426950408889634f);
            s += e[j];
        }
#pragma unroll
        for (int off = 32; off; off >>= 1) s += __shfl_xor(s, off, 64);
        float w4[4];
        if (s > 0.f) {
            const float inv = 1.0f / s;
#pragma unroll
            for (int j = 0; j < 4; ++j) w4[j] = e[j] * inv;
        } else {
#pragma unroll
            for (int j = 0; j < 4; ++j) w4[j] = 1.0f / (float)M_;
        }
#pragma unroll
        for (int j = 0; j < 4; ++j) swt[qi][lane * 4 + j] = w4[j];
        *(float4*)&wout[((b << 8) + (q0 + qi)) * M_ + lane * 4] = *(const float4*)w4;
        if (tid == 0) s_allmask = (s <= 0.f) ? 1 : 0;
    }
    __syncthreads();

    // ---- phase 3: out[q][d] = tanh(Y1[q][d] + sum_m swt[q][m]*Z[b][m][d]) ----
    if (tid < QS_) {
        const int am = s_allmask;
        float a[4] = {0.f, 0.f, 0.f, 0.f};
        const unsigned short* Zrow = &Zb[((b << 8)) * QS_ + tid];
        if (!am) {
            for (int idx = 0; idx < cnt; ++idx) {
                const int m = s_list[idx];
                const float zv = bf2f(Zrow[m * QS_]);
#pragma unroll
                for (int qi = 0; qi < 4; ++qi) a[qi] = fmaf(swt[qi][m], zv, a[qi]);
            }
        } else {
            for (int m = 0; m < M_; ++m) {
                const float zv = bf2f(Zrow[m * QS_]);
#pragma unroll
                for (int qi = 0; qi < 4; ++qi) a[qi] = fmaf(swt[qi][m], zv, a[qi]);
            }
        }
#pragma unroll
        for (int qi = 0; qi < 4; ++qi) {
            const int r = (b << 8) + q0 + qi;
            out[r * QS_ + tid] = tanh_fast(Y1[r * QS_ + tid] + a[qi]);
        }
    }
}

// ---------------------------------------------------------------------------
extern "C" void kernel_launch(void* const* d_in, const int* in_sizes, int n_in,
                              void* d_out, int out_size, void* d_ws, size_t ws_size,
                              hipStream_t stream) {
    const float* query  = (const float*)d_in[0];
    const float* memory = (const float*)d_in[1];
    const void*  mask   = d_in[2];
    const float* Wk = (const float*)d_in[3];
    const float* bk = (const float*)d_in[4];
    const float* Wq = (const float*)d_in[5];
    const float* bq = (const float*)d_in[6];
    const float* Wl = (const float*)d_in[7];
    const float* bl = (const float*)d_in[8];
    const float* Wo = (const float*)d_in[9];
    const float* bo = (const float*)d_in[10];

    float* out  = (float*)d_out;                 // [4,256,512]
    float* wout = out + B_ * Q_ * QS_;           // [4,256,256]

    float* ws = (float*)d_ws;
    float*          Y1    = ws;                              // 524288 f32
    unsigned short* Eqb   = (unsigned short*)(ws + 524288);  // 524288 bf16
    unsigned short* Ekb   = (unsigned short*)(ws + 786432);  // 524288 bf16
    unsigned short* Zb    = (unsigned short*)(ws + 1048576); // 524288 bf16
    unsigned short* qbf   = (unsigned short*)(ws + 1310720); // 524288 bf16
    unsigned short* mbf   = (unsigned short*)(ws + 1572864); // 524288 bf16
    unsigned short* wqbf  = (unsigned short*)(ws + 1835008); // 262144 bf16
    unsigned short* wkbf  = (unsigned short*)(ws + 1966080); // 262144 bf16
    unsigned short* wobf  = (unsigned short*)(ws + 2097152); // 524288 bf16
    int*            maskN = (int*)(ws + 2359296);            // 1024 int

    hipLaunchKernelGGL(prep, dim3(1025), dim3(256), 0, stream,
                       query, memory, Wq, Wk, Wo, (const unsigned char*)mask,
                       qbf, mbf, wqbf, wkbf, wobf, maskN, in_sizes[2]);
    hipLaunchKernelGGL(gemm5, dim3(512), dim3(256), 0, stream,
                       qbf, mbf, wqbf, wkbf, wobf, bq, bk, bo, Eqb, Ekb, Y1, Zb);
    hipLaunchKernelGGL(attn_fused, dim3(Q_ / 4, B_), dim3(1024), 0, stream,
                       maskN, Eqb, Ekb, Wl, bl, Y1, Zb, wout, out);
}

// Round 12
// 47.932 us; speedup vs baseline: 1.3489x; 1.1578x over previous
//
#include <hip/hip_runtime.h>

// ---------------------------------------------------------------------------
// FNNAttention (Bahdanau additive attention). B=4, Q=256, M=256, QS=KS=H=512.
// out = tanh(query@Wo1^T + P@(memory@Wo2^T) + bo),  P = softmax(logits).
// TWO dispatches (fixed replay overhead dominates; R9/R10/R11 nulls show
// kernel interiors are not the bottleneck):
//   1. gemm5 : LDS-staged (fp32->bf16 cvt once per block panel) bf16 MFMA
//              GEMM, 64x64 block tile / 32x32 per wave / k-chunk 128.
//              seg0: Eq=exp2(TSC*(query@Wq^T+bq))  [bf16]
//              seg1: Ek=exp2(TSC*(memory@Wk^T+bk)) [bf16]
//              seg2: Y1=query@Wo1^T+bo             [f32]
//              seg3: Z =memory@Wo2^T               [bf16]
//              block 512: mask normalization (layout-detecting).
//   2. attn  : logits via rcp(Eq*Ek+1) (compacted unmasked-m list), softmax,
//              weights -> wout, out = tanh(Y1 + P@Z).
//              BYTE-IDENTICAL to the replay-proven R11 kernel.
// tanh(x) = 1 - 2/(exp2(TSC*x)+1), TSC = 2*log2(e). MFMA accumulation order
// matches R11's linear k-loop -> output should be bit-identical (absmax
// 0.004882812 is the regression check).
// ---------------------------------------------------------------------------

#define B_   4
#define Q_   256
#define M_   256
#define H_   512
#define QS_  512
#define KS_  512

#define TSC 2.8853900817779268f

typedef __attribute__((ext_vector_type(8))) short bf16x8;
typedef __attribute__((ext_vector_type(4))) float f32x4;

__device__ __forceinline__ float fast_exp2(float x) { return __builtin_amdgcn_exp2f(x); }

__device__ __forceinline__ float tanh_fast(float x) {
    float e = fast_exp2(x * TSC);
    return 1.0f - 2.0f * __builtin_amdgcn_rcpf(e + 1.0f);
}

__device__ __forceinline__ unsigned short rne_bf16(float f) {
    unsigned b = __builtin_bit_cast(unsigned, f);
    return (unsigned short)((b + 0x7FFFu + ((b >> 16) & 1u)) >> 16);
}

__device__ __forceinline__ float bf2f(unsigned short u) {
    return __builtin_bit_cast(float, (unsigned)u << 16);
}

__device__ __forceinline__ bf16x8 cvt8(const float* __restrict__ p) {
    const float4 lo = *(const float4*)p;
    const float4 hi = *(const float4*)(p + 4);
    float f[8] = {lo.x, lo.y, lo.z, lo.w, hi.x, hi.y, hi.z, hi.w};
    union { bf16x8 v; unsigned short u[8]; } r;
#pragma unroll
    for (int j = 0; j < 8; ++j) r.u[j] = rne_bf16(f[j]);
    return r.v;
}

// ---------------------------------------------------------------------------
// gemm5: four batched NT-GEMMs, LDS-staged with in-block fp32->bf16 cvt.
// Block = 256 threads (4 waves, 2x2 of 32x32 tiles), block tile 64x64,
// k-chunk 128 (4 chunks). LDS [64][136] bf16 per operand (pad 8 -> 2-way
// bank aliasing on ds_read_b128, free). grid = 512 gemm blocks + 1 mask.
// Fragment map: A/B lane l -> row/col = l&15, k = kt + (l>>4)*8 + j.
// D: reg j -> row (l>>4)*4+j, col l&15  [measured m89].
// ---------------------------------------------------------------------------
__global__ __launch_bounds__(256) void gemm5(const float* __restrict__ query,
                                             const float* __restrict__ memory,
                                             const float* __restrict__ Wq,
                                             const float* __restrict__ Wk,
                                             const float* __restrict__ Wo,
                                             const float* __restrict__ bq,
                                             const float* __restrict__ bk,
                                             const float* __restrict__ bo,
                                             const unsigned char* __restrict__ mask,
                                             int nmask,
                                             unsigned short* __restrict__ Eqb,
                                             unsigned short* __restrict__ Ekb,
                                             float* __restrict__ Y1,
                                             unsigned short* __restrict__ Zb,
                                             int* __restrict__ maskN) {
    if (blockIdx.x == 512) {  // mask normalization (layout-detecting, r1-proven)
        __shared__ int flags[4];
        const int tid = threadIdx.x;
        int any = 0;
        for (int i = tid; i < nmask; i += 256)
            if ((i & 3) && mask[i]) any = 1;
        int wany = __any(any);
        if ((tid & 63) == 0) flags[tid >> 6] = wany ? 1 : 0;
        __syncthreads();
        const int isbool = flags[0] | flags[1] | flags[2] | flags[3];
        const int* ri = (const int*)mask;
        for (int i = tid; i < nmask; i += 256)
            maskN[i] = isbool ? (int)mask[i] : ri[i];
        return;
    }

    __shared__ unsigned short As[64][136];
    __shared__ unsigned short Ws[64][136];

    const int tid  = threadIdx.x;
    const int lane = tid & 63;
    const int wid  = tid >> 6;
    const int seg  = blockIdx.x >> 7;      // 0..3
    const int sb   = blockIdx.x & 127;
    const int bm   = sb >> 3;              // 0..15 (64-row tiles over 1024)
    const int bn   = sb & 7;               // 0..7  (64-col tiles over 512)

    const float* A;
    const float* W;
    const float* bias;
    int ldW, wko;
    if (seg == 0)      { A = query;  W = Wq; ldW = 512;  wko = 0;   bias = bq; }
    else if (seg == 1) { A = memory; W = Wk; ldW = 512;  wko = 0;   bias = bk; }
    else if (seg == 2) { A = query;  W = Wo; ldW = 1024; wko = 0;   bias = bo; }
    else               { A = memory; W = Wo; ldW = 1024; wko = 512; bias = nullptr; }

    const int wr = wid >> 1;               // 0..1 wave row
    const int wc = wid & 1;                // 0..1 wave col
    const int lr = tid >> 2;               // 0..63 stage row
    const int lq = tid & 3;                // 0..3  stage col group

    const float* Arow = &A[(bm * 64 + lr) * 512];
    const float* Wrow = &W[(bn * 64 + lr) * ldW + wko];

    f32x4 acc00 = {0,0,0,0}, acc01 = {0,0,0,0}, acc10 = {0,0,0,0}, acc11 = {0,0,0,0};

    for (int kt = 0; kt < 512; kt += 128) {
        // ---- stage 128-k chunk: fp32 -> bf16 into LDS (cvt once per panel) ----
#pragma unroll
        for (int j = 0; j < 4; ++j) {
            const int c8 = (lq + 4 * j) * 8;   // 8-elem blocks, 4 threads/row
            *(bf16x8*)&As[lr][c8] = cvt8(&Arow[kt + c8]);
            *(bf16x8*)&Ws[lr][c8] = cvt8(&Wrow[kt + c8]);
        }
        __syncthreads();
        // ---- compute: 4 k-steps of 32 ----
#pragma unroll
        for (int ks = 0; ks < 4; ++ks) {
            const int kk = ks * 32 + (lane >> 4) * 8;
            bf16x8 a0 = *(const bf16x8*)&As[wr * 32 + (lane & 15)][kk];
            bf16x8 a1 = *(const bf16x8*)&As[wr * 32 + 16 + (lane & 15)][kk];
            bf16x8 b0 = *(const bf16x8*)&Ws[wc * 32 + (lane & 15)][kk];
            bf16x8 b1 = *(const bf16x8*)&Ws[wc * 32 + 16 + (lane & 15)][kk];
            acc00 = __builtin_amdgcn_mfma_f32_16x16x32_bf16(a0, b0, acc00, 0, 0, 0);
            acc01 = __builtin_amdgcn_mfma_f32_16x16x32_bf16(a0, b1, acc01, 0, 0, 0);
            acc10 = __builtin_amdgcn_mfma_f32_16x16x32_bf16(a1, b0, acc10, 0, 0, 0);
            acc11 = __builtin_amdgcn_mfma_f32_16x16x32_bf16(a1, b1, acc11, 0, 0, 0);
        }
        __syncthreads();
    }

    const int col = bn * 64 + wc * 32 + (lane & 15);
    const int r0  = bm * 64 + wr * 32 + (lane >> 4) * 4;
    const float bv0 = bias ? bias[col] : 0.f;
    const float bv1 = bias ? bias[col + 16] : 0.f;
    if (seg < 2) {
        unsigned short* E = (seg == 0) ? Eqb : Ekb;
#pragma unroll
        for (int j = 0; j < 4; ++j) {
            E[(r0 + j) * 512 + col]           = rne_bf16(fast_exp2(TSC * (acc00[j] + bv0)));
            E[(r0 + j) * 512 + col + 16]      = rne_bf16(fast_exp2(TSC * (acc01[j] + bv1)));
            E[(r0 + 16 + j) * 512 + col]      = rne_bf16(fast_exp2(TSC * (acc10[j] + bv0)));
            E[(r0 + 16 + j) * 512 + col + 16] = rne_bf16(fast_exp2(TSC * (acc11[j] + bv1)));
        }
    } else if (seg == 2) {
#pragma unroll
        for (int j = 0; j < 4; ++j) {
            Y1[(r0 + j) * 512 + col]           = acc00[j] + bv0;
            Y1[(r0 + j) * 512 + col + 16]      = acc01[j] + bv1;
            Y1[(r0 + 16 + j) * 512 + col]      = acc10[j] + bv0;
            Y1[(r0 + 16 + j) * 512 + col + 16] = acc11[j] + bv1;
        }
    } else {
#pragma unroll
        for (int j = 0; j < 4; ++j) {
            Zb[(r0 + j) * 512 + col]           = rne_bf16(acc00[j]);
            Zb[(r0 + j) * 512 + col + 16]      = rne_bf16(acc01[j]);
            Zb[(r0 + 16 + j) * 512 + col]      = rne_bf16(acc10[j]);
            Zb[(r0 + 16 + j) * 512 + col + 16] = rne_bf16(acc11[j]);
        }
    }
}

// ---------------------------------------------------------------------------
// attn: logits + softmax + final output. Block = (b, 4 q-rows), 1024 threads.
// BYTE-IDENTICAL to the replay-proven R11 kernel.
// ---------------------------------------------------------------------------
__global__ __launch_bounds__(1024) void attn_fused(const int* __restrict__ maskN,
                                                   const unsigned short* __restrict__ Eqb,
                                                   const unsigned short* __restrict__ Ekb,
                                                   const float* __restrict__ Wl,
                                                   const float* __restrict__ bl,
                                                   const float* __restrict__ Y1,
                                                   const unsigned short* __restrict__ Zb,
                                                   float* __restrict__ wout,
                                                   float* __restrict__ out) {
    const int b = blockIdx.y;
    const int q0 = blockIdx.x * 4;
    const int tid = threadIdx.x;
    const int wid = tid >> 6;
    const int lane = tid & 63;

    __shared__ float slog[4][M_];
    __shared__ float swt[4][M_];
    __shared__ int s_list[M_];
    __shared__ int s_base[4];
    __shared__ int s_cnt;
    __shared__ int s_allmask;

    // ---- phase 0: compact unmasked m list ----
    int msk_ = 1, prefix_ = 0;
    if (tid < 256) {
        msk_ = maskN[(b << 8) + tid];
        unsigned long long vote = __ballot(msk_ == 0);
        prefix_ = __popcll(vote & ((1ull << lane) - 1ull));
        if (lane == 0) s_base[wid] = __popcll(vote);
    }
    __syncthreads();
    if (tid == 0) {
        int s = 0;
#pragma unroll
        for (int i = 0; i < 4; ++i) { int c = s_base[i]; s_base[i] = s; s += c; }
        s_cnt = s;
    }
    __syncthreads();
    if (tid < 256 && !msk_) s_list[s_base[wid] + prefix_] = tid;

    // per-lane register slices (Eq already exponentiated, bf16)
    float qreg[4][8], wlr[8];
#pragma unroll
    for (int qi = 0; qi < 4; ++qi) {
        union { bf16x8 v; unsigned short u[8]; } qv;
        qv.v = *(const bf16x8*)&Eqb[((b << 8) + (q0 + qi)) * H_ + lane * 8];
#pragma unroll
        for (int h = 0; h < 8; ++h) qreg[qi][h] = bf2f(qv.u[h]);
    }
    *(float4*)&wlr[0] = *(const float4*)&Wl[lane * 8];
    *(float4*)&wlr[4] = *(const float4*)&Wl[lane * 8 + 4];
    const float bl0 = bl[0];

    float sumWL = wlr[0] + wlr[1] + wlr[2] + wlr[3] + wlr[4] + wlr[5] + wlr[6] + wlr[7];
#pragma unroll
    for (int off = 32; off; off >>= 1) sumWL += __shfl_xor(sumWL, off, 64);

    __syncthreads();
    const int cnt = s_cnt;

    // ---- phase 1: logits over compacted list (1 rcp per element) ----
    for (int idx = wid; idx < cnt; idx += 16) {
        const int m = s_list[idx];
        union { bf16x8 v; unsigned short u[8]; } kv;
        kv.v = *(const bf16x8*)&Ekb[((b << 8) + m) * H_ + lane * 8];
        float acc[4] = {0.f, 0.f, 0.f, 0.f};
#pragma unroll
        for (int h = 0; h < 8; ++h) {
            const float ek = bf2f(kv.u[h]);
            const float wv = wlr[h];
#pragma unroll
            for (int qi = 0; qi < 4; ++qi) {
                const float e = qreg[qi][h] * ek;
                const float r = __builtin_amdgcn_rcpf(e + 1.0f);
                acc[qi] = fmaf(wv, r, acc[qi]);
            }
        }
#pragma unroll
        for (int qi = 0; qi < 4; ++qi) {
            float v = acc[qi];
#pragma unroll
            for (int off = 32; off; off >>= 1) v += __shfl_xor(v, off, 64);
            if (lane == 0) slog[qi][m] = sumWL - 2.0f * v + bl0;
        }
    }
    __syncthreads();

    // ---- phase 2: softmax (wave wid < 4 owns row q0+wid) ----
    if (wid < 4) {
        const int qi = wid;
        float x[4];
        int mk[4];
#pragma unroll
        for (int j = 0; j < 4; ++j) {
            const int m = lane * 4 + j;
            mk[j] = maskN[(b << 8) + m];
            x[j] = mk[j] ? -1e30f : slog[qi][m];
        }
        float mx = fmaxf(fmaxf(x[0], x[1]), fmaxf(x[2], x[3]));
#pragma unroll
        for (int off = 32; off; off >>= 1) mx = fmaxf(mx, __shfl_xor(mx, off, 64));
        float e[4], s = 0.f;
#pragma unroll
        for (int j = 0; j < 4; ++j) {
            e[j] = mk[j] ? 0.f : fast_exp2((x[j] - mx) * 1.4426950408889634f);
            s += e[j];
        }
#pragma unroll
        for (int off = 32; off; off >>= 1) s += __shfl_xor(s, off, 64);
        float w4[4];
        if (s > 0.f) {
            const float inv = 1.0f / s;
#pragma unroll
            for (int j = 0; j < 4; ++j) w4[j] = e[j] * inv;
        } else {
#pragma unroll
            for (int j = 0; j < 4; ++j) w4[j] = 1.0f / (float)M_;
        }
#pragma unroll
        for (int j = 0; j < 4; ++j) swt[qi][lane * 4 + j] = w4[j];
        *(float4*)&wout[((b << 8) + (q0 + qi)) * M_ + lane * 4] = *(const float4*)w4;
        if (tid == 0) s_allmask = (s <= 0.f) ? 1 : 0;
    }
    __syncthreads();

    // ---- phase 3: out[q][d] = tanh(Y1[q][d] + sum_m swt[q][m]*Z[b][m][d]) ----
    if (tid < QS_) {
        const int am = s_allmask;
        float a[4] = {0.f, 0.f, 0.f, 0.f};
        const unsigned short* Zrow = &Zb[((b << 8)) * QS_ + tid];
        if (!am) {
            for (int idx = 0; idx < cnt; ++idx) {
                const int m = s_list[idx];
                const float zv = bf2f(Zrow[m * QS_]);
#pragma unroll
                for (int qi = 0; qi < 4; ++qi) a[qi] = fmaf(swt[qi][m], zv, a[qi]);
            }
        } else {
            for (int m = 0; m < M_; ++m) {
                const float zv = bf2f(Zrow[m * QS_]);
#pragma unroll
                for (int qi = 0; qi < 4; ++qi) a[qi] = fmaf(swt[qi][m], zv, a[qi]);
            }
        }
#pragma unroll
        for (int qi = 0; qi < 4; ++qi) {
            const int r = (b << 8) + q0 + qi;
            out[r * QS_ + tid] = tanh_fast(Y1[r * QS_ + tid] + a[qi]);
        }
    }
}

// ---------------------------------------------------------------------------
extern "C" void kernel_launch(void* const* d_in, const int* in_sizes, int n_in,
                              void* d_out, int out_size, void* d_ws, size_t ws_size,
                              hipStream_t stream) {
    const float* query  = (const float*)d_in[0];
    const float* memory = (const float*)d_in[1];
    const void*  mask   = d_in[2];
    const float* Wk = (const float*)d_in[3];
    const float* bk = (const float*)d_in[4];
    const float* Wq = (const float*)d_in[5];
    const float* bq = (const float*)d_in[6];
    const float* Wl = (const float*)d_in[7];
    const float* bl = (const float*)d_in[8];
    const float* Wo = (const float*)d_in[9];
    const float* bo = (const float*)d_in[10];

    float* out  = (float*)d_out;                 // [4,256,512]
    float* wout = out + B_ * Q_ * QS_;           // [4,256,256]

    float* ws = (float*)d_ws;
    float*          Y1    = ws;                              // 524288 f32
    unsigned short* Eqb   = (unsigned short*)(ws + 524288);  // 524288 bf16
    unsigned short* Ekb   = (unsigned short*)(ws + 786432);  // 524288 bf16
    unsigned short* Zb    = (unsigned short*)(ws + 1048576); // 524288 bf16
    int*            maskN = (int*)(ws + 1310720);            // 1024 int

    hipLaunchKernelGGL(gemm5, dim3(513), dim3(256), 0, stream,
                       query, memory, Wq, Wk, Wo, bq, bk, bo,
                       (const unsigned char*)mask, in_sizes[2],
                       Eqb, Ekb, Y1, Zb, maskN);
    hipLaunchKernelGGL(attn_fused, dim3(Q_ / 4, B_), dim3(1024), 0, stream,
                       maskN, Eqb, Ekb, Wl, bl, Y1, Zb, wout, out);
}